// Round 17
// baseline (223.386 us; speedup 1.0000x reference)
//
#include <hip/hip_runtime.h>

#define NEG 0.2f
#define MAXD 128
#define GEMM_BLOCKS 1024
#define COUNT_BLOCKS 2048

__device__ __forceinline__ float lrelu(float v) { return v > 0.f ? v : NEG * v; }

// round-to-nearest-even fp32 -> bf16 (returns low 16 bits)
__device__ __forceinline__ unsigned f2bf(float f) {
  unsigned u = __float_as_uint(f);
  u = (u + 0x7FFFu + ((u >> 16) & 1u)) >> 16;
  return u;
}
__device__ __forceinline__ float bf_lo(unsigned u) { return __uint_as_float(u << 16); }
__device__ __forceinline__ float bf_hi(unsigned u) { return __uint_as_float(u & 0xFFFF0000u); }

typedef __attribute__((ext_vector_type(8))) short bf16x8;
typedef __attribute__((ext_vector_type(4))) float f32x4;

// ---- Kernel 0: build Bext (bf16, frag order) + zero cnt8 + zero bnpart ----
__global__ __launch_bounds__(256) void k_prep(const float* __restrict__ W,
                                              const float* __restrict__ att_src,
                                              const float* __restrict__ att_dst,
                                              unsigned short* __restrict__ Bext,
                                              int* __restrict__ cnt8, float* __restrict__ bnpart,
                                              int N) {
  const int gtid = blockIdx.x * 256 + threadIdx.x;
  const int gstride = gridDim.x * 256;
  for (int id = gtid; id < 9 * 4 * 64 * 8; id += gstride) {
    int j = id & 7, lane = (id >> 3) & 63, kb = (id >> 9) & 3, ct = id >> 11;
    int k = kb * 32 + (lane >> 4) * 8 + j;
    int c = ct * 16 + (lane & 15);
    float v;
    if (c < 128) {
      v = W[k * 128 + c];
    } else {
      int slot = c - 128;
      int hd = slot & 3;
      const float* att = (slot < 4) ? att_src : att_dst;
      float s = 0.f;
      for (int jj = 0; jj < 32; ++jj) s = fmaf(W[k * 128 + hd * 32 + jj], att[hd * 32 + jj], s);
      v = s;
    }
    Bext[id] = (unsigned short)f2bf(v);
  }
  for (int i = gtid; i < N * 8; i += gstride) cnt8[i] = 0;
  for (int i = gtid; i < 64 * 256; i += gstride) bnpart[i] = 0.f;
}

// ---- Fused kernel, chunk-interleaved roles (8-block chunks keep &7 XCD pinning) ----
__global__ __launch_bounds__(256) void k_gemm_count(
    const float* __restrict__ x, const unsigned short* __restrict__ Bext,
    unsigned* __restrict__ hb, float* __restrict__ a_s, float* __restrict__ a_d,
    int N, int ntiles,
    const int* __restrict__ ei, int* __restrict__ cnt8, int* __restrict__ rank,
    int E, int esh)
{
  const int tid = threadIdx.x;
  const int chunk = blockIdx.x >> 3;
  if (chunk % 3 == 0) {
    // ================= GEMM path =================
    const int vb = (chunk / 3) * 8 + (blockIdx.x & 7);   // [0,1024)
    const bf16x8* Bfrag = reinterpret_cast<const bf16x8*>(Bext);
    const int w = tid >> 6, lane = tid & 63;
    const int r16 = lane & 15, g = lane >> 4;
    for (int tile = vb; tile < ntiles; tile += GEMM_BLOCKS) {
      int n0 = tile * 64 + w * 16;
      int rowc = min(n0 + r16, N - 1);
      const float* xp = x + (size_t)rowc * 128 + g * 8;
      bf16x8 afr[4];
#pragma unroll
      for (int kb = 0; kb < 4; ++kb) {
        float4 lo = *reinterpret_cast<const float4*>(xp + kb * 32);
        float4 hi = *reinterpret_cast<const float4*>(xp + kb * 32 + 4);
        bf16x8 t;
        t[0] = (short)f2bf(lo.x); t[1] = (short)f2bf(lo.y);
        t[2] = (short)f2bf(lo.z); t[3] = (short)f2bf(lo.w);
        t[4] = (short)f2bf(hi.x); t[5] = (short)f2bf(hi.y);
        t[6] = (short)f2bf(hi.z); t[7] = (short)f2bf(hi.w);
        afr[kb] = t;
      }
#pragma unroll
      for (int ct = 0; ct < 9; ++ct) {
        f32x4 acc = {0.f, 0.f, 0.f, 0.f};
#pragma unroll
        for (int kb = 0; kb < 4; ++kb) {
          bf16x8 bfr = Bfrag[(ct * 4 + kb) * 64 + lane];
          acc = __builtin_amdgcn_mfma_f32_16x16x32_bf16(afr[kb], bfr, acc, 0, 0, 0);
        }
        if (ct < 8) {
#pragma unroll
          for (int r = 0; r < 4; ++r) {
            int orow = n0 + g * 4 + r;
            unsigned b = f2bf(acc[r]);
            unsigned partner = __shfl_xor(b, 1);
            if (((lane & 1) == 0) && orow < N)
              hb[((size_t)orow << 6) + ct * 8 + (r16 >> 1)] = b | (partner << 16);
          }
        } else {
#pragma unroll
          for (int r = 0; r < 4; ++r) {
            int orow = n0 + g * 4 + r;
            if (r16 < 8 && orow < N) {
              if (r16 < 4) a_s[orow * 4 + r16] = acc[r];
              else         a_d[orow * 4 + (r16 - 4)] = acc[r];
            }
          }
        }
      }
    }
  } else {
    // ================= count+rank path (edge-partitioned, XCD-private cnt8) =====
    const int r = blockIdx.x & 7;
    const int cidx = chunk - 1 - (chunk / 3);            // [0,256)
    const int qper = 1 << (esh - 2);
    const int ebase = r << esh;
    int* cpriv = cnt8 + (size_t)r * N;
    for (int ql = cidx * 256 + tid; ql < qper; ql += 256 * 256) {
      int e0 = ebase + (ql << 2);
      if (e0 >= E) break;
      if (e0 + 3 < E) {
        int4 d = *reinterpret_cast<const int4*>(ei + E + e0);
        int4 rk;
        rk.x = atomicAdd(&cpriv[d.x], 1);
        rk.y = atomicAdd(&cpriv[d.y], 1);
        rk.z = atomicAdd(&cpriv[d.z], 1);
        rk.w = atomicAdd(&cpriv[d.w], 1);
        *reinterpret_cast<int4*>(rank + e0) = rk;
      } else {
        for (int e = e0; e < E; ++e) {
          int d = ei[E + e];
          rank[e] = atomicAdd(&cpriv[d], 1);
        }
      }
    }
  }
}

// ---- Scan 1 ----
__global__ __launch_bounds__(256) void k_scan1(int* __restrict__ cnt8, int* __restrict__ excl,
                                               int* __restrict__ bsum, int N) {
  __shared__ int sm[256];
  int i = blockIdx.x * 256 + threadIdx.x;
  int tot = 0;
  if (i < N) {
    int run = 0;
#pragma unroll
    for (int r = 0; r < 8; ++r) {
      int t = cnt8[(size_t)r * N + i];
      cnt8[(size_t)r * N + i] = run;
      run += t;
    }
    tot = run;
  }
  sm[threadIdx.x] = tot;
  __syncthreads();
  for (int off = 1; off < 256; off <<= 1) {
    int t = (threadIdx.x >= off) ? sm[threadIdx.x - off] : 0;
    __syncthreads();
    sm[threadIdx.x] += t;
    __syncthreads();
  }
  if (i < N) excl[i] = sm[threadIdx.x] - tot;
  if (threadIdx.x == 255) bsum[blockIdx.x] = sm[255];
}

// ---- Scan 2+3 merged ----
__global__ __launch_bounds__(256) void k_scan23(const int* __restrict__ excl,
                                                const int* __restrict__ bsum,
                                                int* __restrict__ offs, int* __restrict__ cnt8,
                                                int N, int E) {
  __shared__ int red[256];
  const int b = blockIdx.x;
  int partial = 0;
  for (int j = threadIdx.x; j < b; j += 256) partial += bsum[j];
  red[threadIdx.x] = partial;
  __syncthreads();
  for (int off = 128; off >= 1; off >>= 1) {
    if (threadIdx.x < off) red[threadIdx.x] += red[threadIdx.x + off];
    __syncthreads();
  }
  const int base = red[0];
  int i = b * 256 + threadIdx.x;
  if (i < N) {
    int o = base + excl[i];
    offs[i] = o;
#pragma unroll
    for (int r = 0; r < 8; ++r) cnt8[(size_t)r * N + i] += o;
  }
  if (b == 0 && threadIdx.x == 0) offs[N] = E;
}

// ---- XCD-pinned (by dst) ATOMIC-FREE scatter ----
__global__ __launch_bounds__(256) void k_scatter_rank(const int* __restrict__ ei,
                                                      const int* __restrict__ cnt8,
                                                      const int* __restrict__ rank,
                                                      int* __restrict__ ssrc, int E, int rsize,
                                                      int esh, int N) {
  const int r = blockIdx.x & 7;
  const int lo = r * rsize, hi = lo + rsize;
  const int gtid = (blockIdx.x >> 3) * 256 + threadIdx.x;
  const int gstride = (gridDim.x >> 3) * 256;
  const int nquad = E >> 2;
  const int4* dst4 = reinterpret_cast<const int4*>(ei + E);
  const int4* rank4 = reinterpret_cast<const int4*>(rank);
  for (int q = gtid; q < nquad; q += gstride) {
    int4 d = dst4[q];
    int e0 = q << 2;
    const int* sub = cnt8 + (size_t)(e0 >> esh) * N;
    int4 rk = rank4[q];
    if (d.x >= lo && d.x < hi) ssrc[sub[d.x] + rk.x] = ei[e0];
    if (d.y >= lo && d.y < hi) ssrc[sub[d.y] + rk.y] = ei[e0 + 1];
    if (d.z >= lo && d.z < hi) ssrc[sub[d.z] + rk.z] = ei[e0 + 2];
    if (d.w >= lo && d.w < hi) ssrc[sub[d.w] + rk.w] = ei[e0 + 3];
  }
  for (int e = (nquad << 2) + gtid; e < E; e += gstride) {
    int d = ei[E + e];
    if (d >= lo && d < hi) ssrc[cnt8[(size_t)(e >> esh) * N + d] + rank[e]] = ei[e];
  }
}

// ---- k_agg: softmax + aggregation + bias + ELU + BN partials ----
// Pass 2 NEW: 32 lanes span 128 channels (uint2 = 4ch/lane); the two wave-halves
// process TWO edges per instruction stream; halves merged via shfl_xor(32).
__global__ __launch_bounds__(256) void k_agg(
    const unsigned* __restrict__ hb, const float* __restrict__ a_s, const float* __restrict__ a_d,
    const int* __restrict__ offs, const int* __restrict__ ssrc,
    const float* __restrict__ bias, unsigned* __restrict__ preb,
    float* __restrict__ bnpart, int N)
{
  __shared__ float al[4][MAXD][4];
  __shared__ int   ls[4][MAXD];
  __shared__ float sv[4][128];
  const int wv = threadIdx.x >> 6;
  const int lane = threadIdx.x & 63;
  const int n = blockIdx.x * 4 + wv;

  if (n < N) {
    const int start = offs[n], end = offs[n + 1];
    const int deg = end - start;
    const int jm = deg < MAXD ? deg : MAXD;
    float4 adv = *reinterpret_cast<const float4*>(&a_d[n * 4]);
    float4 asv = *reinterpret_cast<const float4*>(&a_s[n * 4]);
    float e0 = __expf(lrelu(asv.x + adv.x));
    float e1 = __expf(lrelu(asv.y + adv.y));
    float e2 = __expf(lrelu(asv.z + adv.z));
    float e3 = __expf(lrelu(asv.w + adv.w));
    // pass 1: striped exp over all edges; cache first MAXD in LDS
    float p0 = 0.f, p1 = 0.f, p2 = 0.f, p3 = 0.f;
    for (int j = lane; j < deg; j += 64) {
      int s = ssrc[start + j];
      float4 av = *reinterpret_cast<const float4*>(&a_s[s * 4]);
      float x0 = __expf(lrelu(av.x + adv.x));
      float x1 = __expf(lrelu(av.y + adv.y));
      float x2 = __expf(lrelu(av.z + adv.z));
      float x3 = __expf(lrelu(av.w + adv.w));
      p0 += x0; p1 += x1; p2 += x2; p3 += x3;
      if (j < MAXD) {
        float4 t = make_float4(x0, x1, x2, x3);
        *reinterpret_cast<float4*>(&al[wv][j][0]) = t;
        ls[wv][j] = s;
      }
    }
#pragma unroll
    for (int off = 32; off >= 1; off >>= 1) {
      p0 += __shfl_xor(p0, off);
      p1 += __shfl_xor(p1, off);
      p2 += __shfl_xor(p2, off);
      p3 += __shfl_xor(p3, off);
    }
    float rden0 = 1.f / (p0 + e0), rden1 = 1.f / (p1 + e1);
    float rden2 = 1.f / (p2 + e2), rden3 = 1.f / (p3 + e3);
    // pre-scale alphas in LDS
    for (int j = lane; j < jm; j += 64) {
      float4 t = *reinterpret_cast<float4*>(&al[wv][j][0]);
      t.x *= rden0; t.y *= rden1; t.z *= rden2; t.w *= rden3;
      *reinterpret_cast<float4*>(&al[wv][j][0]) = t;
    }
    // ---- pass 2 (paired halves) ----
    const int ll = lane & 31;           // channel-lane: 4 channels 4*ll..4*ll+3
    const int hl = ll >> 3;             // head of those channels
    const int cw = ll * 2;              // first u32 word index
    const int half = lane >> 5;         // 0 = even edges, 1 = odd edges
    float rdenl = (hl < 2) ? (hl == 0 ? rden0 : rden1) : (hl == 2 ? rden2 : rden3);
    float esfl  = (hl < 2) ? (hl == 0 ? e0 : e1) : (hl == 2 ? e2 : e3);
    float ad_cl = (hl < 2) ? (hl == 0 ? adv.x : adv.y) : (hl == 2 ? adv.z : adv.w);
    float a0 = 0.f, a1 = 0.f, a2 = 0.f, a3 = 0.f;
    if (half == 0) {  // self-loop on lower half only
      uint2 us = *reinterpret_cast<const uint2*>(&hb[((unsigned)n << 6) + cw]);
      float wself = esfl * rdenl;
      a0 = wself * bf_lo(us.x); a1 = wself * bf_hi(us.x);
      a2 = wself * bf_lo(us.y); a3 = wself * bf_hi(us.y);
    }
    int j2 = 0;
    for (; j2 + 8 <= jm; j2 += 8) {   // 4 pairs = 8 edges per iteration
      int jA = j2 + half, jB = j2 + 2 + half, jC = j2 + 4 + half, jD = j2 + 6 + half;
      int sA = ls[wv][jA], sB = ls[wv][jB], sC = ls[wv][jC], sD = ls[wv][jD];
      uint2 uA = *reinterpret_cast<const uint2*>(&hb[((unsigned)sA << 6) + cw]);
      uint2 uB = *reinterpret_cast<const uint2*>(&hb[((unsigned)sB << 6) + cw]);
      uint2 uC = *reinterpret_cast<const uint2*>(&hb[((unsigned)sC << 6) + cw]);
      uint2 uD = *reinterpret_cast<const uint2*>(&hb[((unsigned)sD << 6) + cw]);
      float wA = al[wv][jA][hl], wB = al[wv][jB][hl];
      float wC = al[wv][jC][hl], wD = al[wv][jD][hl];
      a0 = fmaf(wA, bf_lo(uA.x), a0); a1 = fmaf(wA, bf_hi(uA.x), a1);
      a2 = fmaf(wA, bf_lo(uA.y), a2); a3 = fmaf(wA, bf_hi(uA.y), a3);
      a0 = fmaf(wB, bf_lo(uB.x), a0); a1 = fmaf(wB, bf_hi(uB.x), a1);
      a2 = fmaf(wB, bf_lo(uB.y), a2); a3 = fmaf(wB, bf_hi(uB.y), a3);
      a0 = fmaf(wC, bf_lo(uC.x), a0); a1 = fmaf(wC, bf_hi(uC.x), a1);
      a2 = fmaf(wC, bf_lo(uC.y), a2); a3 = fmaf(wC, bf_hi(uC.y), a3);
      a0 = fmaf(wD, bf_lo(uD.x), a0); a1 = fmaf(wD, bf_hi(uD.x), a1);
      a2 = fmaf(wD, bf_lo(uD.y), a2); a3 = fmaf(wD, bf_hi(uD.y), a3);
    }
    for (; j2 + 2 <= jm; j2 += 2) {   // one pair
      int j = j2 + half;
      int s = ls[wv][j];
      uint2 u = *reinterpret_cast<const uint2*>(&hb[((unsigned)s << 6) + cw]);
      float w = al[wv][j][hl];
      a0 = fmaf(w, bf_lo(u.x), a0); a1 = fmaf(w, bf_hi(u.x), a1);
      a2 = fmaf(w, bf_lo(u.y), a2); a3 = fmaf(w, bf_hi(u.y), a3);
    }
    if (j2 < jm) {                    // odd tail: lower half active, upper w=0
      int s = ls[wv][j2];
      uint2 u = *reinterpret_cast<const uint2*>(&hb[((unsigned)s << 6) + cw]);
      float w = (half == 0) ? al[wv][j2][hl] : 0.f;
      a0 = fmaf(w, bf_lo(u.x), a0); a1 = fmaf(w, bf_hi(u.x), a1);
      a2 = fmaf(w, bf_lo(u.y), a2); a3 = fmaf(w, bf_hi(u.y), a3);
    }
    // overflow edges (deg > MAXD): paired recompute path
    for (int jj = MAXD; jj < deg; jj += 2) {
      int j = jj + half;
      bool act = j < deg;
      int s = ssrc[start + (act ? j : jj)];
      float q = a_s[s * 4 + hl];
      float w = act ? __expf(lrelu(q + ad_cl)) * rdenl : 0.f;
      uint2 u = *reinterpret_cast<const uint2*>(&hb[((unsigned)s << 6) + cw]);
      a0 = fmaf(w, bf_lo(u.x), a0); a1 = fmaf(w, bf_hi(u.x), a1);
      a2 = fmaf(w, bf_lo(u.y), a2); a3 = fmaf(w, bf_hi(u.y), a3);
    }
    // merge halves
    a0 += __shfl_xor(a0, 32);
    a1 += __shfl_xor(a1, 32);
    a2 += __shfl_xor(a2, 32);
    a3 += __shfl_xor(a3, 32);
    if (half == 0) {
      float4 bv = *reinterpret_cast<const float4*>(&bias[4 * ll]);
      float o0 = a0 + bv.x, o1 = a1 + bv.y, o2 = a2 + bv.z, o3 = a3 + bv.w;
      o0 = o0 > 0.f ? o0 : expm1f(o0);
      o1 = o1 > 0.f ? o1 : expm1f(o1);
      o2 = o2 > 0.f ? o2 : expm1f(o2);
      o3 = o3 > 0.f ? o3 : expm1f(o3);
      uint2 pw;
      pw.x = f2bf(o0) | (f2bf(o1) << 16);
      pw.y = f2bf(o2) | (f2bf(o3) << 16);
      *reinterpret_cast<uint2*>(&preb[((size_t)n << 6) + cw]) = pw;
      *reinterpret_cast<float4*>(&sv[wv][4 * ll]) = make_float4(o0, o1, o2, o3);
    }
  } else {
    if (lane < 32) *reinterpret_cast<float4*>(&sv[wv][4 * lane]) = make_float4(0.f, 0.f, 0.f, 0.f);
  }
  __syncthreads();
  // BN partial sums: 128 threads reduce 4 nodes per channel
  int t = threadIdx.x;
  if (t < 128) {
    float s = 0.f, q = 0.f;
#pragma unroll
    for (int w2 = 0; w2 < 4; ++w2) {
      float v = sv[w2][t];
      s += v;
      q = fmaf(v, v, q);
    }
    float* slot = bnpart + (size_t)(blockIdx.x & 63) * 256;
    atomicAdd(&slot[t], s);
    atomicAdd(&slot[128 + t], q);
  }
}

// ---- BN scale/shift from partials ----
__global__ void k_bnfinal(const float* __restrict__ bnpart,
                          const float* __restrict__ gamma, const float* __restrict__ beta,
                          float* __restrict__ sc, float* __restrict__ sh, int N) {
  int c = threadIdx.x;
  float s = 0.f, q = 0.f;
  for (int p = 0; p < 64; ++p) {
    s += bnpart[p * 256 + c];
    q += bnpart[p * 256 + 128 + c];
  }
  float invn = 1.f / (float)N;
  float mean = s * invn;
  float var = q * invn - mean * mean;
  float scl = gamma[c] * rsqrtf(var + 1e-5f);
  sc[c] = scl;
  sh[c] = beta[c] - mean * scl;
}

// ---- apply BN: read packed bf16 pre, write fp32 out ----
__global__ __launch_bounds__(256) void k_bnapply(const unsigned* __restrict__ preb,
                                                 float* __restrict__ out,
                                                 const float* __restrict__ sc,
                                                 const float* __restrict__ sh, int npair2) {
  int i = blockIdx.x * blockDim.x + threadIdx.x;
  if (i >= npair2) return;
  uint2 u = reinterpret_cast<const uint2*>(preb)[i];
  int p0 = i * 2;
  int c0 = (p0 & 63) * 2;
  float4 scv = *reinterpret_cast<const float4*>(&sc[c0]);
  float4 shv = *reinterpret_cast<const float4*>(&sh[c0]);
  float4 v;
  v.x = fmaf(bf_lo(u.x), scv.x, shv.x);
  v.y = fmaf(bf_hi(u.x), scv.y, shv.y);
  v.z = fmaf(bf_lo(u.y), scv.z, shv.z);
  v.w = fmaf(bf_hi(u.y), scv.w, shv.w);
  reinterpret_cast<float4*>(out)[i] = v;
}

extern "C" void kernel_launch(void* const* d_in, const int* in_sizes, int n_in,
                              void* d_out, int out_size, void* d_ws, size_t ws_size,
                              hipStream_t stream) {
  const float* x = (const float*)d_in[0];
  const int* ei = (const int*)d_in[1];
  const float* W = (const float*)d_in[2];
  const float* att_src = (const float*)d_in[3];
  const float* att_dst = (const float*)d_in[4];
  const float* bias = (const float*)d_in[5];
  const float* gamma = (const float*)d_in[6];
  const float* beta = (const float*)d_in[7];
  float* out = (float*)d_out;

  const int N = in_sizes[0] / 128;
  const int E = in_sizes[1] / 2;

  char* ws = (char*)d_ws;
  size_t off = 0;
  auto alloc = [&](size_t bytes) {
    void* p = ws + off;
    off = (off + bytes + 255) & ~(size_t)255;
    return p;
  };
  unsigned* hb = (unsigned*)alloc((size_t)N * 64 * 4);
  float* a_s = (float*)alloc((size_t)N * 4 * 4);
  float* a_d = (float*)alloc((size_t)N * 4 * 4);
  int* excl = (int*)alloc((size_t)N * 4);
  int* offs = (int*)alloc((size_t)(N + 1) * 4);
  int* bsum = (int*)alloc(512 * 4);
  int* rank = (int*)alloc((size_t)E * 4);
  int* ssrc = (int*)alloc((size_t)E * 4);
  unsigned* preb = (unsigned*)alloc((size_t)N * 64 * 4);
  float* bnpart = (float*)alloc(64 * 256 * 4);
  float* sc = (float*)alloc(128 * 4);
  float* sh = (float*)alloc(128 * 4);
  unsigned short* Bext = (unsigned short*)alloc(9 * 4 * 64 * 8 * 2);
  (void)n_in; (void)out_size; (void)ws_size;

  int* cnt8 = (int*)preb;  // aliases preb; dead before k_agg writes preb

  int esh = 10;
  while (((E + (1 << esh) - 1) >> esh) > 8) ++esh;

  k_prep<<<64, 256, 0, stream>>>(W, att_src, att_dst, Bext, cnt8, bnpart, N);

  int ntiles = (N + 63) / 64;
  k_gemm_count<<<GEMM_BLOCKS + COUNT_BLOCKS, 256, 0, stream>>>(
      x, Bext, hb, a_s, a_d, N, ntiles, ei, cnt8, rank, E, esh);

  int nb = (N + 255) / 256;
  k_scan1<<<nb, 256, 0, stream>>>(cnt8, excl, bsum, N);
  k_scan23<<<nb, 256, 0, stream>>>(excl, bsum, offs, cnt8, N, E);

  int rsize = (N + 7) / 8;
  k_scatter_rank<<<2048, 256, 0, stream>>>(ei, cnt8, rank, ssrc, E, rsize, esh, N);

  k_agg<<<(N + 3) / 4, 256, 0, stream>>>(hb, a_s, a_d, offs, ssrc, bias, preb, bnpart, N);

  k_bnfinal<<<1, 128, 0, stream>>>(bnpart, gamma, beta, sc, sh, N);

  int npair2 = N * 32;
  k_bnapply<<<(npair2 + 255) / 256, 256, 0, stream>>>(preb, out, sc, sh, npair2);
}

// Round 18
// 219.494 us; speedup vs baseline: 1.0177x; 1.0177x over previous
//
#include <hip/hip_runtime.h>

#define NEG 0.2f
#define MAXD 128
#define GEMM_BLOCKS 1024
#define COUNT_BLOCKS 2048

__device__ __forceinline__ float lrelu(float v) { return v > 0.f ? v : NEG * v; }

// round-to-nearest-even fp32 -> bf16 (returns low 16 bits)
__device__ __forceinline__ unsigned f2bf(float f) {
  unsigned u = __float_as_uint(f);
  u = (u + 0x7FFFu + ((u >> 16) & 1u)) >> 16;
  return u;
}
__device__ __forceinline__ float bf_lo(unsigned u) { return __uint_as_float(u << 16); }
__device__ __forceinline__ float bf_hi(unsigned u) { return __uint_as_float(u & 0xFFFF0000u); }

typedef __attribute__((ext_vector_type(8))) short bf16x8;
typedef __attribute__((ext_vector_type(4))) float f32x4;

// ---- Kernel 0: build Bext (bf16, frag order) + zero cnt8 + zero bnpart ----
__global__ __launch_bounds__(256) void k_prep(const float* __restrict__ W,
                                              const float* __restrict__ att_src,
                                              const float* __restrict__ att_dst,
                                              unsigned short* __restrict__ Bext,
                                              int* __restrict__ cnt8, float* __restrict__ bnpart,
                                              int N) {
  const int gtid = blockIdx.x * 256 + threadIdx.x;
  const int gstride = gridDim.x * 256;
  for (int id = gtid; id < 9 * 4 * 64 * 8; id += gstride) {
    int j = id & 7, lane = (id >> 3) & 63, kb = (id >> 9) & 3, ct = id >> 11;
    int k = kb * 32 + (lane >> 4) * 8 + j;
    int c = ct * 16 + (lane & 15);
    float v;
    if (c < 128) {
      v = W[k * 128 + c];
    } else {
      int slot = c - 128;
      int hd = slot & 3;
      const float* att = (slot < 4) ? att_src : att_dst;
      float s = 0.f;
      for (int jj = 0; jj < 32; ++jj) s = fmaf(W[k * 128 + hd * 32 + jj], att[hd * 32 + jj], s);
      v = s;
    }
    Bext[id] = (unsigned short)f2bf(v);
  }
  for (int i = gtid; i < N * 8; i += gstride) cnt8[i] = 0;
  for (int i = gtid; i < 64 * 256; i += gstride) bnpart[i] = 0.f;
}

// ---- Fused kernel, chunk-interleaved roles (8-block chunks keep &7 XCD pinning) ----
__global__ __launch_bounds__(256) void k_gemm_count(
    const float* __restrict__ x, const unsigned short* __restrict__ Bext,
    unsigned* __restrict__ hb, float* __restrict__ a_s, float* __restrict__ a_d,
    int N, int ntiles,
    const int* __restrict__ ei, int* __restrict__ cnt8, int* __restrict__ rank,
    int E, int esh)
{
  const int tid = threadIdx.x;
  const int chunk = blockIdx.x >> 3;
  if (chunk % 3 == 0) {
    // ================= GEMM path =================
    const int vb = (chunk / 3) * 8 + (blockIdx.x & 7);   // [0,1024)
    const bf16x8* Bfrag = reinterpret_cast<const bf16x8*>(Bext);
    const int w = tid >> 6, lane = tid & 63;
    const int r16 = lane & 15, g = lane >> 4;
    for (int tile = vb; tile < ntiles; tile += GEMM_BLOCKS) {
      int n0 = tile * 64 + w * 16;
      int rowc = min(n0 + r16, N - 1);
      const float* xp = x + (size_t)rowc * 128 + g * 8;
      bf16x8 afr[4];
#pragma unroll
      for (int kb = 0; kb < 4; ++kb) {
        float4 lo = *reinterpret_cast<const float4*>(xp + kb * 32);
        float4 hi = *reinterpret_cast<const float4*>(xp + kb * 32 + 4);
        bf16x8 t;
        t[0] = (short)f2bf(lo.x); t[1] = (short)f2bf(lo.y);
        t[2] = (short)f2bf(lo.z); t[3] = (short)f2bf(lo.w);
        t[4] = (short)f2bf(hi.x); t[5] = (short)f2bf(hi.y);
        t[6] = (short)f2bf(hi.z); t[7] = (short)f2bf(hi.w);
        afr[kb] = t;
      }
#pragma unroll
      for (int ct = 0; ct < 9; ++ct) {
        f32x4 acc = {0.f, 0.f, 0.f, 0.f};
#pragma unroll
        for (int kb = 0; kb < 4; ++kb) {
          bf16x8 bfr = Bfrag[(ct * 4 + kb) * 64 + lane];
          acc = __builtin_amdgcn_mfma_f32_16x16x32_bf16(afr[kb], bfr, acc, 0, 0, 0);
        }
        if (ct < 8) {
#pragma unroll
          for (int r = 0; r < 4; ++r) {
            int orow = n0 + g * 4 + r;
            unsigned b = f2bf(acc[r]);
            unsigned partner = __shfl_xor(b, 1);
            if (((lane & 1) == 0) && orow < N)
              hb[((size_t)orow << 6) + ct * 8 + (r16 >> 1)] = b | (partner << 16);
          }
        } else {
#pragma unroll
          for (int r = 0; r < 4; ++r) {
            int orow = n0 + g * 4 + r;
            if (r16 < 8 && orow < N) {
              if (r16 < 4) a_s[orow * 4 + r16] = acc[r];
              else         a_d[orow * 4 + (r16 - 4)] = acc[r];
            }
          }
        }
      }
    }
  } else {
    // ================= count+rank path (edge-partitioned, XCD-private cnt8) =====
    const int r = blockIdx.x & 7;
    const int cidx = chunk - 1 - (chunk / 3);            // [0,256)
    const int qper = 1 << (esh - 2);
    const int ebase = r << esh;
    int* cpriv = cnt8 + (size_t)r * N;
    for (int ql = cidx * 256 + tid; ql < qper; ql += 256 * 256) {
      int e0 = ebase + (ql << 2);
      if (e0 >= E) break;
      if (e0 + 3 < E) {
        int4 d = *reinterpret_cast<const int4*>(ei + E + e0);
        int4 rk;
        rk.x = atomicAdd(&cpriv[d.x], 1);
        rk.y = atomicAdd(&cpriv[d.y], 1);
        rk.z = atomicAdd(&cpriv[d.z], 1);
        rk.w = atomicAdd(&cpriv[d.w], 1);
        *reinterpret_cast<int4*>(rank + e0) = rk;
      } else {
        for (int e = e0; e < E; ++e) {
          int d = ei[E + e];
          rank[e] = atomicAdd(&cpriv[d], 1);
        }
      }
    }
  }
}

// ---- Scan 1 ----
__global__ __launch_bounds__(256) void k_scan1(int* __restrict__ cnt8, int* __restrict__ excl,
                                               int* __restrict__ bsum, int N) {
  __shared__ int sm[256];
  int i = blockIdx.x * 256 + threadIdx.x;
  int tot = 0;
  if (i < N) {
    int run = 0;
#pragma unroll
    for (int r = 0; r < 8; ++r) {
      int t = cnt8[(size_t)r * N + i];
      cnt8[(size_t)r * N + i] = run;
      run += t;
    }
    tot = run;
  }
  sm[threadIdx.x] = tot;
  __syncthreads();
  for (int off = 1; off < 256; off <<= 1) {
    int t = (threadIdx.x >= off) ? sm[threadIdx.x - off] : 0;
    __syncthreads();
    sm[threadIdx.x] += t;
    __syncthreads();
  }
  if (i < N) excl[i] = sm[threadIdx.x] - tot;
  if (threadIdx.x == 255) bsum[blockIdx.x] = sm[255];
}

// ---- Scan 2+3 merged ----
__global__ __launch_bounds__(256) void k_scan23(const int* __restrict__ excl,
                                                const int* __restrict__ bsum,
                                                int* __restrict__ offs, int* __restrict__ cnt8,
                                                int N, int E) {
  __shared__ int red[256];
  const int b = blockIdx.x;
  int partial = 0;
  for (int j = threadIdx.x; j < b; j += 256) partial += bsum[j];
  red[threadIdx.x] = partial;
  __syncthreads();
  for (int off = 128; off >= 1; off >>= 1) {
    if (threadIdx.x < off) red[threadIdx.x] += red[threadIdx.x + off];
    __syncthreads();
  }
  const int base = red[0];
  int i = b * 256 + threadIdx.x;
  if (i < N) {
    int o = base + excl[i];
    offs[i] = o;
#pragma unroll
    for (int r = 0; r < 8; ++r) cnt8[(size_t)r * N + i] += o;
  }
  if (b == 0 && threadIdx.x == 0) offs[N] = E;
}

// ---- XCD-pinned (by dst) ATOMIC-FREE scatter ----
__global__ __launch_bounds__(256) void k_scatter_rank(const int* __restrict__ ei,
                                                      const int* __restrict__ cnt8,
                                                      const int* __restrict__ rank,
                                                      int* __restrict__ ssrc, int E, int rsize,
                                                      int esh, int N) {
  const int r = blockIdx.x & 7;
  const int lo = r * rsize, hi = lo + rsize;
  const int gtid = (blockIdx.x >> 3) * 256 + threadIdx.x;
  const int gstride = (gridDim.x >> 3) * 256;
  const int nquad = E >> 2;
  const int4* dst4 = reinterpret_cast<const int4*>(ei + E);
  const int4* rank4 = reinterpret_cast<const int4*>(rank);
  for (int q = gtid; q < nquad; q += gstride) {
    int4 d = dst4[q];
    int e0 = q << 2;
    const int* sub = cnt8 + (size_t)(e0 >> esh) * N;
    int4 rk = rank4[q];
    if (d.x >= lo && d.x < hi) ssrc[sub[d.x] + rk.x] = ei[e0];
    if (d.y >= lo && d.y < hi) ssrc[sub[d.y] + rk.y] = ei[e0 + 1];
    if (d.z >= lo && d.z < hi) ssrc[sub[d.z] + rk.z] = ei[e0 + 2];
    if (d.w >= lo && d.w < hi) ssrc[sub[d.w] + rk.w] = ei[e0 + 3];
  }
  for (int e = (nquad << 2) + gtid; e < E; e += gstride) {
    int d = ei[E + e];
    if (d >= lo && d < hi) ssrc[cnt8[(size_t)(e >> esh) * N + d] + rank[e]] = ei[e];
  }
}

// ---- k_agg: softmax + aggregation + bias + ELU + BN partials (round-16 pass2 + 16-deep unroll) ----
// wave per node; lane owns channels (2*lane, 2*lane+1), head = lane>>4
__global__ __launch_bounds__(256) void k_agg(
    const unsigned* __restrict__ hb, const float* __restrict__ a_s, const float* __restrict__ a_d,
    const int* __restrict__ offs, const int* __restrict__ ssrc,
    const float* __restrict__ bias, unsigned* __restrict__ preb,
    float* __restrict__ bnpart, int N)
{
  __shared__ float al[4][MAXD][4];
  __shared__ int   ls[4][MAXD];
  __shared__ float sv[4][128];
  const int wv = threadIdx.x >> 6;
  const int lane = threadIdx.x & 63;
  const int n = blockIdx.x * 4 + wv;

  if (n < N) {
    const int hsel = lane >> 4;
    const int start = offs[n], end = offs[n + 1];
    const int deg = end - start;
    const int jm = deg < MAXD ? deg : MAXD;
    float4 adv = *reinterpret_cast<const float4*>(&a_d[n * 4]);
    float4 asv = *reinterpret_cast<const float4*>(&a_s[n * 4]);
    float e0 = __expf(lrelu(asv.x + adv.x));
    float e1 = __expf(lrelu(asv.y + adv.y));
    float e2 = __expf(lrelu(asv.z + adv.z));
    float e3 = __expf(lrelu(asv.w + adv.w));
    // pass 1: striped exp over all edges; cache first MAXD in LDS
    float p0 = 0.f, p1 = 0.f, p2 = 0.f, p3 = 0.f;
    for (int j = lane; j < deg; j += 64) {
      int s = ssrc[start + j];
      float4 av = *reinterpret_cast<const float4*>(&a_s[s * 4]);
      float x0 = __expf(lrelu(av.x + adv.x));
      float x1 = __expf(lrelu(av.y + adv.y));
      float x2 = __expf(lrelu(av.z + adv.z));
      float x3 = __expf(lrelu(av.w + adv.w));
      p0 += x0; p1 += x1; p2 += x2; p3 += x3;
      if (j < MAXD) {
        float4 t = make_float4(x0, x1, x2, x3);
        *reinterpret_cast<float4*>(&al[wv][j][0]) = t;
        ls[wv][j] = s;
      }
    }
#pragma unroll
    for (int off = 32; off >= 1; off >>= 1) {
      p0 += __shfl_xor(p0, off);
      p1 += __shfl_xor(p1, off);
      p2 += __shfl_xor(p2, off);
      p3 += __shfl_xor(p3, off);
    }
    float rden0 = 1.f / (p0 + e0), rden1 = 1.f / (p1 + e1);
    float rden2 = 1.f / (p2 + e2), rden3 = 1.f / (p3 + e3);
    // pre-scale alphas in LDS
    for (int j = lane; j < jm; j += 64) {
      float4 t = *reinterpret_cast<float4*>(&al[wv][j][0]);
      t.x *= rden0; t.y *= rden1; t.z *= rden2; t.w *= rden3;
      *reinterpret_cast<float4*>(&al[wv][j][0]) = t;
    }
    float ad_c = (hsel < 2) ? (hsel == 0 ? adv.x : adv.y) : (hsel == 2 ? adv.z : adv.w);
    float rden = (hsel < 2) ? (hsel == 0 ? rden0 : rden1) : (hsel == 2 ? rden2 : rden3);
    float esf = (hsel < 2) ? (hsel == 0 ? e0 : e1) : (hsel == 2 ? e2 : e3);
    // pass 2: self + gathers weighted by cached alpha (16 then 8 loads in flight)
    unsigned us = hb[((unsigned)n << 6) + lane];
    float wself = esf * rden;
    float acc0 = wself * bf_lo(us);
    float acc1 = wself * bf_hi(us);
    int j = 0;
    for (; j + 16 <= jm; j += 16) {
      int4 sA = *reinterpret_cast<int4*>(&ls[wv][j]);
      int4 sB = *reinterpret_cast<int4*>(&ls[wv][j + 4]);
      int4 sC = *reinterpret_cast<int4*>(&ls[wv][j + 8]);
      int4 sD = *reinterpret_cast<int4*>(&ls[wv][j + 12]);
      unsigned u0 = hb[((unsigned)sA.x << 6) + lane];
      unsigned u1 = hb[((unsigned)sA.y << 6) + lane];
      unsigned u2 = hb[((unsigned)sA.z << 6) + lane];
      unsigned u3 = hb[((unsigned)sA.w << 6) + lane];
      unsigned u4 = hb[((unsigned)sB.x << 6) + lane];
      unsigned u5 = hb[((unsigned)sB.y << 6) + lane];
      unsigned u6 = hb[((unsigned)sB.z << 6) + lane];
      unsigned u7 = hb[((unsigned)sB.w << 6) + lane];
      unsigned u8 = hb[((unsigned)sC.x << 6) + lane];
      unsigned u9 = hb[((unsigned)sC.y << 6) + lane];
      unsigned uA2 = hb[((unsigned)sC.z << 6) + lane];
      unsigned uB2 = hb[((unsigned)sC.w << 6) + lane];
      unsigned uC2 = hb[((unsigned)sD.x << 6) + lane];
      unsigned uD2 = hb[((unsigned)sD.y << 6) + lane];
      unsigned uE2 = hb[((unsigned)sD.z << 6) + lane];
      unsigned uF2 = hb[((unsigned)sD.w << 6) + lane];
      float w0 = al[wv][j][hsel];
      float w1 = al[wv][j + 1][hsel];
      float w2 = al[wv][j + 2][hsel];
      float w3 = al[wv][j + 3][hsel];
      float w4 = al[wv][j + 4][hsel];
      float w5 = al[wv][j + 5][hsel];
      float w6 = al[wv][j + 6][hsel];
      float w7 = al[wv][j + 7][hsel];
      float w8 = al[wv][j + 8][hsel];
      float w9 = al[wv][j + 9][hsel];
      float wA = al[wv][j + 10][hsel];
      float wB = al[wv][j + 11][hsel];
      float wC = al[wv][j + 12][hsel];
      float wD = al[wv][j + 13][hsel];
      float wE = al[wv][j + 14][hsel];
      float wF = al[wv][j + 15][hsel];
      acc0 = fmaf(w0, bf_lo(u0), acc0);  acc1 = fmaf(w0, bf_hi(u0), acc1);
      acc0 = fmaf(w1, bf_lo(u1), acc0);  acc1 = fmaf(w1, bf_hi(u1), acc1);
      acc0 = fmaf(w2, bf_lo(u2), acc0);  acc1 = fmaf(w2, bf_hi(u2), acc1);
      acc0 = fmaf(w3, bf_lo(u3), acc0);  acc1 = fmaf(w3, bf_hi(u3), acc1);
      acc0 = fmaf(w4, bf_lo(u4), acc0);  acc1 = fmaf(w4, bf_hi(u4), acc1);
      acc0 = fmaf(w5, bf_lo(u5), acc0);  acc1 = fmaf(w5, bf_hi(u5), acc1);
      acc0 = fmaf(w6, bf_lo(u6), acc0);  acc1 = fmaf(w6, bf_hi(u6), acc1);
      acc0 = fmaf(w7, bf_lo(u7), acc0);  acc1 = fmaf(w7, bf_hi(u7), acc1);
      acc0 = fmaf(w8, bf_lo(u8), acc0);  acc1 = fmaf(w8, bf_hi(u8), acc1);
      acc0 = fmaf(w9, bf_lo(u9), acc0);  acc1 = fmaf(w9, bf_hi(u9), acc1);
      acc0 = fmaf(wA, bf_lo(uA2), acc0); acc1 = fmaf(wA, bf_hi(uA2), acc1);
      acc0 = fmaf(wB, bf_lo(uB2), acc0); acc1 = fmaf(wB, bf_hi(uB2), acc1);
      acc0 = fmaf(wC, bf_lo(uC2), acc0); acc1 = fmaf(wC, bf_hi(uC2), acc1);
      acc0 = fmaf(wD, bf_lo(uD2), acc0); acc1 = fmaf(wD, bf_hi(uD2), acc1);
      acc0 = fmaf(wE, bf_lo(uE2), acc0); acc1 = fmaf(wE, bf_hi(uE2), acc1);
      acc0 = fmaf(wF, bf_lo(uF2), acc0); acc1 = fmaf(wF, bf_hi(uF2), acc1);
    }
    for (; j + 8 <= jm; j += 8) {
      int4 sA = *reinterpret_cast<int4*>(&ls[wv][j]);
      int4 sB = *reinterpret_cast<int4*>(&ls[wv][j + 4]);
      unsigned u0 = hb[((unsigned)sA.x << 6) + lane];
      unsigned u1 = hb[((unsigned)sA.y << 6) + lane];
      unsigned u2 = hb[((unsigned)sA.z << 6) + lane];
      unsigned u3 = hb[((unsigned)sA.w << 6) + lane];
      unsigned u4 = hb[((unsigned)sB.x << 6) + lane];
      unsigned u5 = hb[((unsigned)sB.y << 6) + lane];
      unsigned u6 = hb[((unsigned)sB.z << 6) + lane];
      unsigned u7 = hb[((unsigned)sB.w << 6) + lane];
      float w0 = al[wv][j][hsel];
      float w1 = al[wv][j + 1][hsel];
      float w2 = al[wv][j + 2][hsel];
      float w3 = al[wv][j + 3][hsel];
      float w4 = al[wv][j + 4][hsel];
      float w5 = al[wv][j + 5][hsel];
      float w6 = al[wv][j + 6][hsel];
      float w7 = al[wv][j + 7][hsel];
      acc0 = fmaf(w0, bf_lo(u0), acc0);
      acc1 = fmaf(w0, bf_hi(u0), acc1);
      acc0 = fmaf(w1, bf_lo(u1), acc0);
      acc1 = fmaf(w1, bf_hi(u1), acc1);
      acc0 = fmaf(w2, bf_lo(u2), acc0);
      acc1 = fmaf(w2, bf_hi(u2), acc1);
      acc0 = fmaf(w3, bf_lo(u3), acc0);
      acc1 = fmaf(w3, bf_hi(u3), acc1);
      acc0 = fmaf(w4, bf_lo(u4), acc0);
      acc1 = fmaf(w4, bf_hi(u4), acc1);
      acc0 = fmaf(w5, bf_lo(u5), acc0);
      acc1 = fmaf(w5, bf_hi(u5), acc1);
      acc0 = fmaf(w6, bf_lo(u6), acc0);
      acc1 = fmaf(w6, bf_hi(u6), acc1);
      acc0 = fmaf(w7, bf_lo(u7), acc0);
      acc1 = fmaf(w7, bf_hi(u7), acc1);
    }
    for (; j + 4 <= jm; j += 4) {
      int4 s4 = *reinterpret_cast<int4*>(&ls[wv][j]);
      unsigned u0 = hb[((unsigned)s4.x << 6) + lane];
      unsigned u1 = hb[((unsigned)s4.y << 6) + lane];
      unsigned u2 = hb[((unsigned)s4.z << 6) + lane];
      unsigned u3 = hb[((unsigned)s4.w << 6) + lane];
      float w0 = al[wv][j][hsel];
      float w1 = al[wv][j + 1][hsel];
      float w2 = al[wv][j + 2][hsel];
      float w3 = al[wv][j + 3][hsel];
      acc0 = fmaf(w0, bf_lo(u0), acc0);
      acc1 = fmaf(w0, bf_hi(u0), acc1);
      acc0 = fmaf(w1, bf_lo(u1), acc0);
      acc1 = fmaf(w1, bf_hi(u1), acc1);
      acc0 = fmaf(w2, bf_lo(u2), acc0);
      acc1 = fmaf(w2, bf_hi(u2), acc1);
      acc0 = fmaf(w3, bf_lo(u3), acc0);
      acc1 = fmaf(w3, bf_hi(u3), acc1);
    }
    for (; j < jm; ++j) {
      int s = ls[wv][j];
      float w = al[wv][j][hsel];
      unsigned u = hb[((unsigned)s << 6) + lane];
      acc0 = fmaf(w, bf_lo(u), acc0);
      acc1 = fmaf(w, bf_hi(u), acc1);
    }
    // overflow edges (deg > MAXD): recompute path
    for (int jj = MAXD; jj < deg; ++jj) {
      int s = ssrc[start + jj];
      float q = a_s[s * 4 + hsel];
      unsigned u = hb[((unsigned)s << 6) + lane];
      float w = __expf(lrelu(q + ad_c)) * rden;
      acc0 = fmaf(w, bf_lo(u), acc0);
      acc1 = fmaf(w, bf_hi(u), acc1);
    }
    float2 bv = *reinterpret_cast<const float2*>(&bias[2 * lane]);
    float o0 = acc0 + bv.x;
    float o1 = acc1 + bv.y;
    o0 = o0 > 0.f ? o0 : expm1f(o0);
    o1 = o1 > 0.f ? o1 : expm1f(o1);
    preb[((size_t)n << 6) + lane] = f2bf(o0) | (f2bf(o1) << 16);
    sv[wv][2 * lane] = o0;
    sv[wv][2 * lane + 1] = o1;
  } else {
    sv[wv][2 * lane] = 0.f;
    sv[wv][2 * lane + 1] = 0.f;
  }
  __syncthreads();
  // BN partial sums: 128 threads reduce 4 nodes per channel
  int t = threadIdx.x;
  if (t < 128) {
    float s = 0.f, q = 0.f;
#pragma unroll
    for (int w2 = 0; w2 < 4; ++w2) {
      float v = sv[w2][t];
      s += v;
      q = fmaf(v, v, q);
    }
    float* slot = bnpart + (size_t)(blockIdx.x & 63) * 256;
    atomicAdd(&slot[t], s);
    atomicAdd(&slot[128 + t], q);
  }
}

// ---- BN scale/shift from partials ----
__global__ void k_bnfinal(const float* __restrict__ bnpart,
                          const float* __restrict__ gamma, const float* __restrict__ beta,
                          float* __restrict__ sc, float* __restrict__ sh, int N) {
  int c = threadIdx.x;
  float s = 0.f, q = 0.f;
  for (int p = 0; p < 64; ++p) {
    s += bnpart[p * 256 + c];
    q += bnpart[p * 256 + 128 + c];
  }
  float invn = 1.f / (float)N;
  float mean = s * invn;
  float var = q * invn - mean * mean;
  float scl = gamma[c] * rsqrtf(var + 1e-5f);
  sc[c] = scl;
  sh[c] = beta[c] - mean * scl;
}

// ---- apply BN: read packed bf16 pre, write fp32 out ----
__global__ __launch_bounds__(256) void k_bnapply(const unsigned* __restrict__ preb,
                                                 float* __restrict__ out,
                                                 const float* __restrict__ sc,
                                                 const float* __restrict__ sh, int npair2) {
  int i = blockIdx.x * blockDim.x + threadIdx.x;
  if (i >= npair2) return;
  uint2 u = reinterpret_cast<const uint2*>(preb)[i];
  int p0 = i * 2;
  int c0 = (p0 & 63) * 2;
  float4 scv = *reinterpret_cast<const float4*>(&sc[c0]);
  float4 shv = *reinterpret_cast<const float4*>(&sh[c0]);
  float4 v;
  v.x = fmaf(bf_lo(u.x), scv.x, shv.x);
  v.y = fmaf(bf_hi(u.x), scv.y, shv.y);
  v.z = fmaf(bf_lo(u.y), scv.z, shv.z);
  v.w = fmaf(bf_hi(u.y), scv.w, shv.w);
  reinterpret_cast<float4*>(out)[i] = v;
}

extern "C" void kernel_launch(void* const* d_in, const int* in_sizes, int n_in,
                              void* d_out, int out_size, void* d_ws, size_t ws_size,
                              hipStream_t stream) {
  const float* x = (const float*)d_in[0];
  const int* ei = (const int*)d_in[1];
  const float* W = (const float*)d_in[2];
  const float* att_src = (const float*)d_in[3];
  const float* att_dst = (const float*)d_in[4];
  const float* bias = (const float*)d_in[5];
  const float* gamma = (const float*)d_in[6];
  const float* beta = (const float*)d_in[7];
  float* out = (float*)d_out;

  const int N = in_sizes[0] / 128;
  const int E = in_sizes[1] / 2;

  char* ws = (char*)d_ws;
  size_t off = 0;
  auto alloc = [&](size_t bytes) {
    void* p = ws + off;
    off = (off + bytes + 255) & ~(size_t)255;
    return p;
  };
  unsigned* hb = (unsigned*)alloc((size_t)N * 64 * 4);
  float* a_s = (float*)alloc((size_t)N * 4 * 4);
  float* a_d = (float*)alloc((size_t)N * 4 * 4);
  int* excl = (int*)alloc((size_t)N * 4);
  int* offs = (int*)alloc((size_t)(N + 1) * 4);
  int* bsum = (int*)alloc(512 * 4);
  int* rank = (int*)alloc((size_t)E * 4);
  int* ssrc = (int*)alloc((size_t)E * 4);
  unsigned* preb = (unsigned*)alloc((size_t)N * 64 * 4);
  float* bnpart = (float*)alloc(64 * 256 * 4);
  float* sc = (float*)alloc(128 * 4);
  float* sh = (float*)alloc(128 * 4);
  unsigned short* Bext = (unsigned short*)alloc(9 * 4 * 64 * 8 * 2);
  (void)n_in; (void)out_size; (void)ws_size;

  int* cnt8 = (int*)preb;  // aliases preb; dead before k_agg writes preb

  int esh = 10;
  while (((E + (1 << esh) - 1) >> esh) > 8) ++esh;

  k_prep<<<64, 256, 0, stream>>>(W, att_src, att_dst, Bext, cnt8, bnpart, N);

  int ntiles = (N + 63) / 64;
  k_gemm_count<<<GEMM_BLOCKS + COUNT_BLOCKS, 256, 0, stream>>>(
      x, Bext, hb, a_s, a_d, N, ntiles, ei, cnt8, rank, E, esh);

  int nb = (N + 255) / 256;
  k_scan1<<<nb, 256, 0, stream>>>(cnt8, excl, bsum, N);
  k_scan23<<<nb, 256, 0, stream>>>(excl, bsum, offs, cnt8, N, E);

  int rsize = (N + 7) / 8;
  k_scatter_rank<<<2048, 256, 0, stream>>>(ei, cnt8, rank, ssrc, E, rsize, esh, N);

  k_agg<<<(N + 3) / 4, 256, 0, stream>>>(hb, a_s, a_d, offs, ssrc, bias, preb, bnpart, N);

  k_bnfinal<<<1, 128, 0, stream>>>(bnpart, gamma, beta, sc, sh, N);

  int npair2 = N * 32;
  k_bnapply<<<(npair2 + 255) / 256, 256, 0, stream>>>(preb, out, sc, sh, npair2);
}